// Round 1
// baseline (87.609 us; speedup 1.0000x reference)
//
#include <hip/hip_runtime.h>
#include <math.h>

// Geodesic correction, fully analytic (Christoffel contraction collapses since
// v_k v_i is symmetric):  corr = -Hess(g).grad(g),  g(x) = v . mlp(x).
// Per interior point:
//   z = W1^T x + b1 ; t = tanh z ; s = 1-t^2 ; c = W2 v
//   p = c*s ; grad = W1 p ; r = W1^T grad ; q = -2c*t*s ; w = q*r ; corr = -W1 w
//
// Round-9: merge R8's two kernels into ONE graph node. Each block first
// produces one (b, 256-h chunk) slice of Z0/Zd/C (and, for b==0 blocks, the
// fp8 W1 chunk), publishes with an agent-scope release flag, then polls the
// 16 flags its point depends on and runs the R8 k_fused body verbatim.
// Residency: 256 blocks = 256 CUs; 1024-thr blocks force <=128 VGPR so every
// block fits one CU -> all co-resident -> handshake always completes. A
// poll-timeout fallback reproduces missing chunks locally (benign identical-
// value races) so even pathological scheduling terminates correctly.
// Accounting: saves one ~3.3us graph node + prep/fused serialization.

#define D64   64
#define CHUNK 256
#define MAGIC 0x3C96A5E1u

typedef float floatx2 __attribute__((ext_vector_type(2)));

__device__ __forceinline__ floatx2 fp8_lo(unsigned u) {   // bytes 0,1 -> f32
    return __builtin_amdgcn_cvt_pk_f32_fp8(u, false);
}
__device__ __forceinline__ floatx2 fp8_hi(unsigned u) {   // bytes 2,3 -> f32
    return __builtin_amdgcn_cvt_pk_f32_fp8(u, true);
}
__device__ __forceinline__ unsigned char f2fp8(float x) {
    return (unsigned char)(__builtin_amdgcn_cvt_pk_fp8_f32(x, 0.f, 0, false) & 0xFF);
}

__global__ __launch_bounds__(1024) void k_geo(
    const float* __restrict__ x0, const float* __restrict__ xT,
    const float* __restrict__ W1, const float* __restrict__ b1,
    const float* __restrict__ W2,
    unsigned char* __restrict__ W1q,
    float* __restrict__ Z0, float* __restrict__ Zd, float* __restrict__ C,
    unsigned int* __restrict__ flags,   // [B*NCH] Z-chunk flags | [NCH] W1q flags
    float* __restrict__ out, int B, int H, int n_steps)
{
    const int n    = blockIdx.x;
    const int tid  = threadIdx.x;
    const int lane = tid & 63;
    const int wv   = tid >> 6;            // 16 waves
    const int NCH  = H / CHUNK;           // 8

    __shared__ float x0L[D64], dL[D64], vL[D64];
    __shared__ float pL[2048];            // p, then reused for w
    __shared__ float qL[2048];
    __shared__ float gradL[D64];
    __shared__ float corrL[D64];
    __shared__ unsigned int missL;

    // ================= phase 1: produce chunk (b_p, hx) =================
    const int b_p = n / NCH;
    const int hx  = n % NCH;
    if (b_p < B) {
        if (tid < D64) {
            const float a0 = x0[b_p * D64 + tid];
            const float aT = xT[b_p * D64 + tid];
            const float d  = aT - a0;
            float ss = d * d;
            #pragma unroll
            for (int off = 32; off; off >>= 1) ss += __shfl_xor(ss, off);
            const float inv = 1.0f / sqrtf(ss);
            x0L[tid] = a0; dL[tid] = d; vL[tid] = d * inv;
        }
        __syncthreads();
        if (tid < CHUNK) {
            const int h = hx * CHUNK + tid;
            float z0 = b1[h];
            float zd = 0.f;
            if (b_p == 0) {               // b==0 blocks also emit fp8 W1 chunk
                #pragma unroll 8
                for (int d = 0; d < D64; ++d) {
                    const float w = W1[(size_t)d * H + h];
                    W1q[(size_t)d * H + h] = f2fp8(w);
                    z0 = fmaf(x0L[d], w, z0);
                    zd = fmaf(dL[d],  w, zd);
                }
            } else {
                #pragma unroll 8
                for (int d = 0; d < D64; ++d) {
                    const float w = W1[(size_t)d * H + h];
                    z0 = fmaf(x0L[d], w, z0);
                    zd = fmaf(dL[d],  w, zd);
                }
            }
            float c = 0.f;
            const float4* w2r = reinterpret_cast<const float4*>(W2 + (size_t)h * D64);
            #pragma unroll
            for (int i = 0; i < D64 / 4; ++i) {
                const float4 w = w2r[i];
                c = fmaf(w.x, vL[4*i],     c);
                c = fmaf(w.y, vL[4*i + 1], c);
                c = fmaf(w.z, vL[4*i + 2], c);
                c = fmaf(w.w, vL[4*i + 3], c);
            }
            Z0[(size_t)b_p * H + h] = z0;
            Zd[(size_t)b_p * H + h] = zd;
            C [(size_t)b_p * H + h] = c;
        }
        __syncthreads();   // compiler drains vmcnt before s_barrier -> stores in L2
        if (tid == 0) {    // agent-release: wbl2 makes chunk visible cross-XCD
            __hip_atomic_store(&flags[b_p * NCH + hx], MAGIC,
                               __ATOMIC_RELEASE, __HIP_MEMORY_SCOPE_AGENT);
            if (b_p == 0)
                __hip_atomic_store(&flags[B * NCH + hx], MAGIC,
                                   __ATOMIC_RELEASE, __HIP_MEMORY_SCOPE_AGENT);
        }
    }

    // ================= phase 2: one interior point per block =============
    const int s8 = n / B;
    const int b  = n % B;
    const float ts = (float)(s8 + 1) / (float)(n_steps - 1);

    if (s8 == 0 && tid < D64) {          // edge rows: one block set per b
        const float a0 = x0[b * D64 + tid];
        const float aT = xT[b * D64 + tid];
        out[(size_t)(0 * B + b) * D64 + tid]             = a0;
        out[(size_t)((n_steps - 1) * B + b) * D64 + tid] = aT;
    }

    // ---- wait for deps: 8 Z-chunks of this b + 8 W1q chunks ----
    if (wv == 0) {
        const bool need = lane < 2 * NCH;
        unsigned int* addr = need
            ? (lane < NCH ? &flags[b * NCH + lane] : &flags[B * NCH + (lane - NCH)])
            : &flags[0];
        bool ok = !need;
        int iter = 0;
        while (true) {
            if (!ok) ok = (__hip_atomic_load(addr, __ATOMIC_RELAXED,
                                             __HIP_MEMORY_SCOPE_AGENT) == MAGIC);
            if (__all(ok)) { if (lane == 0) missL = 0u; break; }
            if (++iter > 60000) {        // residency insurance; never expected
                const unsigned long long bal = __ballot(ok);
                if (lane == 0) missL = (unsigned)(~bal) & 0xFFFFu;
                break;
            }
            __builtin_amdgcn_s_sleep(2);
        }
        if (need && ok)                  // agent-acquire: invalidate L1/L2
            (void)__hip_atomic_load(addr, __ATOMIC_ACQUIRE, __HIP_MEMORY_SCOPE_AGENT);
    }
    __syncthreads();
    const unsigned miss = missL;
    if (miss) {   // fallback: produce missing chunks ourselves (identical-value races are benign)
        if (tid < D64) {
            const float a0 = x0[b * D64 + tid];
            const float aT = xT[b * D64 + tid];
            const float d  = aT - a0;
            float ss = d * d;
            #pragma unroll
            for (int off = 32; off; off >>= 1) ss += __shfl_xor(ss, off);
            const float inv = 1.0f / sqrtf(ss);
            x0L[tid] = a0; dL[tid] = d; vL[tid] = d * inv;
        }
        __syncthreads();
        for (int k = 0; k < NCH; ++k) {
            if ((miss & (1u << k)) && tid < CHUNK) {
                const int h = k * CHUNK + tid;
                float z0 = b1[h], zd = 0.f;
                #pragma unroll 8
                for (int d = 0; d < D64; ++d) {
                    const float w = W1[(size_t)d * H + h];
                    z0 = fmaf(x0L[d], w, z0);
                    zd = fmaf(dL[d],  w, zd);
                }
                float c = 0.f;
                const float4* w2r = reinterpret_cast<const float4*>(W2 + (size_t)h * D64);
                #pragma unroll
                for (int i = 0; i < D64 / 4; ++i) {
                    const float4 w = w2r[i];
                    c = fmaf(w.x, vL[4*i],   c); c = fmaf(w.y, vL[4*i+1], c);
                    c = fmaf(w.z, vL[4*i+2], c); c = fmaf(w.w, vL[4*i+3], c);
                }
                Z0[(size_t)b * H + h] = z0;
                Zd[(size_t)b * H + h] = zd;
                C [(size_t)b * H + h] = c;
            }
            if ((miss & (1u << (NCH + k))) && tid < CHUNK) {
                const int h = k * CHUNK + tid;
                #pragma unroll 8
                for (int d = 0; d < D64; ++d)
                    W1q[(size_t)d * H + h] = f2fp8(W1[(size_t)d * H + h]);
            }
        }
        __syncthreads();
    }

    // ---- rebuild p, q for this point (2 h's per thread) ----
    {
        const float2 z0 = reinterpret_cast<const float2*>(Z0 + (size_t)b * H)[tid];
        const float2 zd = reinterpret_cast<const float2*>(Zd + (size_t)b * H)[tid];
        const float2 c  = reinterpret_cast<const float2*>(C  + (size_t)b * H)[tid];
        const float zx = fmaf(ts, zd.x, z0.x);
        const float zy = fmaf(ts, zd.y, z0.y);
        const float tx = tanhf(zx), ty = tanhf(zy);
        const float sx = 1.f - tx * tx, sy = 1.f - ty * ty;
        pL[2 * tid]     = c.x * sx;
        pL[2 * tid + 1] = c.y * sy;
        qL[2 * tid]     = -2.f * c.x * tx * sx;
        qL[2 * tid + 1] = -2.f * c.y * ty * sy;
    }
    __syncthreads();

    // ---- grad_a = sum_h W1[a,h] p_h : wave wv -> rows 4wv..4wv+3 ----
    #pragma unroll
    for (int rr = 0; rr < 4; ++rr) {
        const int a = wv * 4 + rr;
        const unsigned* wrow = reinterpret_cast<const unsigned*>(W1q + (size_t)a * H);
        float acc = 0.f;
        #pragma unroll
        for (int j = 0; j < 8; ++j) {     // k = 4*lane + 256*j
            const unsigned w  = wrow[lane + j * 64];       // fp8 k..k+3
            const float4   p  = reinterpret_cast<const float4*>(pL)[lane + j * 64];
            const floatx2  w0 = fp8_lo(w);
            const floatx2  w1 = fp8_hi(w);
            acc = fmaf(w0.x, p.x, acc);
            acc = fmaf(w0.y, p.y, acc);
            acc = fmaf(w1.x, p.z, acc);
            acc = fmaf(w1.y, p.w, acc);
        }
        #pragma unroll
        for (int off = 32; off; off >>= 1) acc += __shfl_xor(acc, off);
        if (lane == 0) gradL[a] = acc;
    }
    __syncthreads();

    // ---- r_h = sum_d W1[d,h] grad_d ; w_h = q_h * r_h (into pL) ----
    {
        float2 r = make_float2(0.f, 0.f);
        #pragma unroll 16
        for (int d = 0; d < D64; ++d) {
            const unsigned w = *reinterpret_cast<const unsigned short*>(
                                   W1q + (size_t)d * H + 2 * tid);
            const floatx2 wf = fp8_lo(w);          // bytes 0,1 = h, h+1
            const float    g = gradL[d];           // LDS broadcast: free
            r.x = fmaf(g, wf.x, r.x);
            r.y = fmaf(g, wf.y, r.y);
        }
        pL[2 * tid]     = qL[2 * tid]     * r.x;
        pL[2 * tid + 1] = qL[2 * tid + 1] * r.y;
    }
    __syncthreads();

    // ---- corr_a = -sum_h W1[a,h] w_h ----
    #pragma unroll
    for (int rr = 0; rr < 4; ++rr) {
        const int a = wv * 4 + rr;
        const unsigned* wrow = reinterpret_cast<const unsigned*>(W1q + (size_t)a * H);
        float acc = 0.f;
        #pragma unroll
        for (int j = 0; j < 8; ++j) {
            const unsigned w  = wrow[lane + j * 64];
            const float4   p  = reinterpret_cast<const float4*>(pL)[lane + j * 64];
            const floatx2  w0 = fp8_lo(w);
            const floatx2  w1 = fp8_hi(w);
            acc = fmaf(w0.x, p.x, acc);
            acc = fmaf(w0.y, p.y, acc);
            acc = fmaf(w1.x, p.z, acc);
            acc = fmaf(w1.y, p.w, acc);
        }
        #pragma unroll
        for (int off = 32; off; off >>= 1) acc += __shfl_xor(acc, off);
        if (lane == 0) corrL[a] = -acc;
    }
    __syncthreads();

    // ---- epilogue (wave 0): scale & write ----
    if (tid < D64) {
        const float a0 = x0[b * D64 + tid];
        const float aT = xT[b * D64 + tid];
        const float d  = aT - a0;
        const float cm = corrL[tid];
        float n2 = cm * cm;
        #pragma unroll
        for (int off = 32; off; off >>= 1) n2 += __shfl_xor(n2, off);
        const float scale  = fminf(sqrtf(n2), 0.1f);
        const float factor = ts * (1.f - ts) * scale * 0.1f;
        out[(size_t)((s8 + 1) * B + b) * D64 + tid] = fmaf(cm, factor, fmaf(ts, d, a0));
    }
}

extern "C" void kernel_launch(void* const* d_in, const int* in_sizes, int n_in,
                              void* d_out, int out_size, void* d_ws, size_t ws_size,
                              hipStream_t stream) {
    const float* x0 = (const float*)d_in[0];
    const float* xT = (const float*)d_in[1];
    const float* W1 = (const float*)d_in[2];
    const float* b1 = (const float*)d_in[3];
    const float* W2 = (const float*)d_in[4];
    float* out = (float*)d_out;

    const int H       = in_sizes[3];            // 2048
    const int D       = in_sizes[2] / H;        // 64
    const int B       = in_sizes[0] / D;        // 32
    const int n_steps = out_size / (B * D);     // 10
    const int NI      = n_steps - 2;            // 8
    const int NP      = NI * B;                 // 256 == B * (H/CHUNK)

    // ws layout: W1q[D*H] fp8 | Z0[B*H] f32 | Zd[B*H] f32 | C[B*H] f32 | flags
    unsigned char* W1q = (unsigned char*)d_ws;
    float* Z0 = (float*)(W1q + (size_t)D * H);  // 128 KB offset, 4B-aligned
    float* Zd = Z0 + (size_t)B * H;
    float* C  = Zd + (size_t)B * H;
    unsigned int* flags = (unsigned int*)(C + (size_t)B * H);  // re-poisoned
                                                               // each iter ->
                                                               // handshake re-arms

    k_geo<<<dim3(NP), dim3(1024), 0, stream>>>(
        x0, xT, W1, b1, W2, W1q, Z0, Zd, C, flags, out, B, H, n_steps);
}

// Round 3
// 81.032 us; speedup vs baseline: 1.0812x; 1.0812x over previous
//
#include <hip/hip_runtime.h>
#include <math.h>

// Geodesic correction, fully analytic (Christoffel contraction collapses since
// v_k v_i is symmetric):  corr = -Hess(g).grad(g),  g(x) = v . mlp(x).
// Per interior point:
//   z = W1^T x + b1 ; t = tanh z ; s = 1-t^2 ; c = W2 v
//   p = c*s ; grad = W1 p ; r = W1^T grad ; q = -2c*t*s ; w = q*r ; corr = -W1 w
//
// Round-11 == Round-10 resubmitted (R10 bench was GPUAcquisitionTimeout;
// kernel never ran). Two-kernel structure (R9's merged handshake regressed:
// agent-scope release/acquire = L2 wb/inv on gfx950, kills W1q locality).
// Exec micro-opts vs R8:
//   - k_fused stages W1q into LDS once (async global_load_lds x8, hidden
//     under the p/q rebuild); all three passes read LDS, not L2.
//   - floatx2 accumulators -> v_pk_fma_f32 packed math in the passes.
//   - k_prep: 512-thread blocks, d-loop split across two halves (latency /2).
// Accounting model (fits R2-R8): dur = 40 us ws-poison fill (harness-fixed)
// + ~3.3 us/graph-node (8 harness + 2 ours) + kernel exec (~7 us -> ~5.5 us).

#define D64 64

typedef float floatx2 __attribute__((ext_vector_type(2)));

__device__ __forceinline__ floatx2 fp8_lo(unsigned u) {   // bytes 0,1 -> f32
    return __builtin_amdgcn_cvt_pk_f32_fp8(u, false);
}
__device__ __forceinline__ floatx2 fp8_hi(unsigned u) {   // bytes 2,3 -> f32
    return __builtin_amdgcn_cvt_pk_f32_fp8(u, true);
}
__device__ __forceinline__ unsigned char f2fp8(float x) {
    return (unsigned char)(__builtin_amdgcn_cvt_pk_fp8_f32(x, 0.f, 0, false) & 0xFF);
}

// ---- K0: Z0, Zd, C per b; W1->fp8 and edge rows from b==0 blocks ----
// grid (H/256, B), block 512: half 0 does d=0..31, half 1 does d=32..63,
// partials combined through LDS. Halves the 64-deep L2-latency chain and
// doubles waves/CU (4 -> 8) for hiding.
__global__ __launch_bounds__(512) void k_prep(
    const float* __restrict__ x0, const float* __restrict__ xT,
    const float* __restrict__ W1, const float* __restrict__ b1,
    const float* __restrict__ W2,
    unsigned char* __restrict__ W1q,
    float* __restrict__ Z0, float* __restrict__ Zd, float* __restrict__ C,
    float* __restrict__ out, int B, int H, int n_steps)
{
    const int b    = blockIdx.y;
    const int tid  = threadIdx.x;
    const int t8   = tid & 255;
    const int half = tid >> 8;                 // 0 or 1
    const int h    = blockIdx.x * 256 + t8;

    __shared__ float x0L[D64], dL[D64], vL[D64];
    __shared__ float pz0[256], pzd[256], pc[256];

    if (tid < D64) {
        const float a0 = x0[b * D64 + tid];
        const float aT = xT[b * D64 + tid];
        const float d  = aT - a0;
        float ss = d * d;
        #pragma unroll
        for (int off = 32; off; off >>= 1) ss += __shfl_xor(ss, off);
        const float inv = 1.0f / sqrtf(ss);
        x0L[tid] = a0; dL[tid] = d; vL[tid] = d * inv;
        if (blockIdx.x == 0) {   // edge rows: s=0 -> x0, s=n_steps-1 -> xT
            out[(size_t)(0 * B + b) * D64 + tid]             = a0;
            out[(size_t)((n_steps - 1) * B + b) * D64 + tid] = aT;
        }
    }
    __syncthreads();

    const int d0 = half * 32;
    float z0 = half ? 0.f : b1[h];
    float zd = 0.f;
    if (b == 0) {                 // also emit fp8 W1 (grid-uniform branch)
        #pragma unroll
        for (int d = d0; d < d0 + 32; ++d) {
            const float w = W1[(size_t)d * H + h];
            W1q[(size_t)d * H + h] = f2fp8(w);
            z0 = fmaf(x0L[d], w, z0);
            zd = fmaf(dL[d],  w, zd);
        }
    } else {
        #pragma unroll
        for (int d = d0; d < d0 + 32; ++d) {
            const float w = W1[(size_t)d * H + h];
            z0 = fmaf(x0L[d], w, z0);
            zd = fmaf(dL[d],  w, zd);
        }
    }

    float c = 0.f;
    const float4* w2r = reinterpret_cast<const float4*>(W2 + (size_t)h * D64 + d0);
    #pragma unroll
    for (int i = 0; i < 8; ++i) {
        const float4 w = w2r[i];
        c = fmaf(w.x, vL[d0 + 4*i],     c);
        c = fmaf(w.y, vL[d0 + 4*i + 1], c);
        c = fmaf(w.z, vL[d0 + 4*i + 2], c);
        c = fmaf(w.w, vL[d0 + 4*i + 3], c);
    }

    if (half) { pz0[t8] = z0; pzd[t8] = zd; pc[t8] = c; }
    __syncthreads();
    if (!half) {
        Z0[(size_t)b * H + h] = z0 + pz0[t8];
        Zd[(size_t)b * H + h] = zd + pzd[t8];
        C [(size_t)b * H + h] = c  + pc[t8];
    }
}

// ---- K1: fused p/q rebuild + grad/r/w/corr/output, one block per point ----
// grid NP=256, block 1024 (16 waves). W1q staged to LDS once (async, hidden
// under the rebuild), all three passes read LDS. floatx2 accs -> pk_fma.
// LDS: 128K w1s + 8K pL + 8K qL + 0.5K = ~145 KB (1 block/CU — grid=256
// blocks on 256 CUs, so occupancy is 1 block/CU regardless).
__global__ __launch_bounds__(1024) void k_fused(
    const float* __restrict__ x0, const float* __restrict__ xT,
    const unsigned char* __restrict__ W1q,
    const float* __restrict__ Z0, const float* __restrict__ Zd,
    const float* __restrict__ C,
    float* __restrict__ out, int B, int H, int n_steps)
{
    const int n    = blockIdx.x;          // (s-1)*B + b
    const int s8   = n / B;
    const int b    = n % B;
    const int tid  = threadIdx.x;
    const int lane = tid & 63;
    const int wv   = tid >> 6;            // 16 waves

    __shared__ unsigned char w1s[D64 * 2048];   // fp8 W1, 128 KB
    __shared__ float pL[2048];            // p, then reused for w
    __shared__ float qL[2048];
    __shared__ float gradL[D64];
    __shared__ float corrL[D64];

    const float ts = (float)(s8 + 1) / (float)(n_steps - 1);

    // ---- async stage W1q -> LDS: 8 x (16 B/lane) per wave, linear layout.
    // Issued first so the loads fly while the rebuild below computes tanh.
    #pragma unroll
    for (int j = 0; j < 8; ++j) {
        const int loff = j * 16384 + wv * 1024;            // wave-uniform dst
        __builtin_amdgcn_global_load_lds(
            (const __attribute__((address_space(1))) void*)(W1q + loff + lane * 16),
            (__attribute__((address_space(3))) void*)(w1s + loff),
            16, 0, 0);
    }

    // ---- rebuild p, q for this point (2 h's per thread) ----
    {
        const float2 z0 = reinterpret_cast<const float2*>(Z0 + (size_t)b * H)[tid];
        const float2 zd = reinterpret_cast<const float2*>(Zd + (size_t)b * H)[tid];
        const float2 c  = reinterpret_cast<const float2*>(C  + (size_t)b * H)[tid];
        const float zx = fmaf(ts, zd.x, z0.x);
        const float zy = fmaf(ts, zd.y, z0.y);
        const float tx = tanhf(zx), ty = tanhf(zy);
        const float sx = 1.f - tx * tx, sy = 1.f - ty * ty;
        pL[2 * tid]     = c.x * sx;
        pL[2 * tid + 1] = c.y * sy;
        qL[2 * tid]     = -2.f * c.x * tx * sx;
        qL[2 * tid + 1] = -2.f * c.y * ty * sy;
    }
    __syncthreads();   // drains vmcnt -> w1s complete; pL/qL visible

    // ---- grad_a = sum_h W1[a,h] p_h : wave wv -> rows 4wv..4wv+3 ----
    #pragma unroll
    for (int rr = 0; rr < 4; ++rr) {
        const int a = wv * 4 + rr;
        const unsigned* wrow = reinterpret_cast<const unsigned*>(w1s + a * 2048);
        floatx2 acc2 = {0.f, 0.f};
        #pragma unroll
        for (int j = 0; j < 8; ++j) {     // k = 4*lane + 256*j
            const unsigned w  = wrow[lane + j * 64];       // fp8 k..k+3 (LDS)
            const float4   p  = reinterpret_cast<const float4*>(pL)[lane + j * 64];
            const floatx2  w0 = fp8_lo(w);
            const floatx2  w1 = fp8_hi(w);
            floatx2 p01; p01.x = p.x; p01.y = p.y;
            floatx2 p23; p23.x = p.z; p23.y = p.w;
            acc2 = w0 * p01 + acc2;       // v_pk_fma_f32
            acc2 = w1 * p23 + acc2;
        }
        float acc = acc2.x + acc2.y;
        #pragma unroll
        for (int off = 32; off; off >>= 1) acc += __shfl_xor(acc, off);
        if (lane == 0) gradL[a] = acc;
    }
    __syncthreads();

    // ---- r_h = sum_d W1[d,h] grad_d ; w_h = q_h * r_h (into pL) ----
    {
        floatx2 r2 = {0.f, 0.f};
        #pragma unroll 16
        for (int d = 0; d < D64; ++d) {
            const unsigned short ws = *reinterpret_cast<const unsigned short*>(
                                          w1s + d * 2048 + 2 * tid);
            const floatx2 wf = fp8_lo((unsigned)ws);   // bytes 0,1 = h, h+1
            const float    g = gradL[d];               // LDS broadcast: free
            floatx2 g2; g2.x = g; g2.y = g;
            r2 = wf * g2 + r2;                         // v_pk_fma_f32
        }
        pL[2 * tid]     = qL[2 * tid]     * r2.x;
        pL[2 * tid + 1] = qL[2 * tid + 1] * r2.y;
    }
    __syncthreads();

    // ---- corr_a = -sum_h W1[a,h] w_h ----
    #pragma unroll
    for (int rr = 0; rr < 4; ++rr) {
        const int a = wv * 4 + rr;
        const unsigned* wrow = reinterpret_cast<const unsigned*>(w1s + a * 2048);
        floatx2 acc2 = {0.f, 0.f};
        #pragma unroll
        for (int j = 0; j < 8; ++j) {
            const unsigned w  = wrow[lane + j * 64];
            const float4   p  = reinterpret_cast<const float4*>(pL)[lane + j * 64];
            const floatx2  w0 = fp8_lo(w);
            const floatx2  w1 = fp8_hi(w);
            floatx2 p01; p01.x = p.x; p01.y = p.y;
            floatx2 p23; p23.x = p.z; p23.y = p.w;
            acc2 = w0 * p01 + acc2;
            acc2 = w1 * p23 + acc2;
        }
        float acc = acc2.x + acc2.y;
        #pragma unroll
        for (int off = 32; off; off >>= 1) acc += __shfl_xor(acc, off);
        if (lane == 0) corrL[a] = -acc;
    }
    __syncthreads();

    // ---- epilogue (wave 0): scale & write ----
    if (tid < D64) {
        const float a0 = x0[b * D64 + tid];
        const float aT = xT[b * D64 + tid];
        const float d  = aT - a0;
        const float cm = corrL[tid];
        float n2 = cm * cm;
        #pragma unroll
        for (int off = 32; off; off >>= 1) n2 += __shfl_xor(n2, off);
        const float scale  = fminf(sqrtf(n2), 0.1f);
        const float factor = ts * (1.f - ts) * scale * 0.1f;
        out[(size_t)((s8 + 1) * B + b) * D64 + tid] = fmaf(cm, factor, fmaf(ts, d, a0));
    }
}

extern "C" void kernel_launch(void* const* d_in, const int* in_sizes, int n_in,
                              void* d_out, int out_size, void* d_ws, size_t ws_size,
                              hipStream_t stream) {
    const float* x0 = (const float*)d_in[0];
    const float* xT = (const float*)d_in[1];
    const float* W1 = (const float*)d_in[2];
    const float* b1 = (const float*)d_in[3];
    const float* W2 = (const float*)d_in[4];
    float* out = (float*)d_out;

    const int H       = in_sizes[3];            // 2048
    const int D       = in_sizes[2] / H;        // 64
    const int B       = in_sizes[0] / D;        // 32
    const int n_steps = out_size / (B * D);     // 10
    const int NI      = n_steps - 2;            // 8
    const int NP      = NI * B;                 // 256

    // ws layout: W1q[D*H] fp8 | Z0[B*H] f32 | Zd[B*H] f32 | C[B*H] f32
    unsigned char* W1q = (unsigned char*)d_ws;
    float* Z0 = (float*)(W1q + (size_t)D * H);  // 128 KB offset, 4B-aligned
    float* Zd = Z0 + (size_t)B * H;
    float* C  = Zd + (size_t)B * H;

    k_prep<<<dim3(H / 256, B), dim3(512), 0, stream>>>(
        x0, xT, W1, b1, W2, W1q, Z0, Zd, C, out, B, H, n_steps);
    k_fused<<<dim3(NP), dim3(1024), 0, stream>>>(
        x0, xT, W1q, Z0, Zd, C, out, B, H, n_steps);
}

// Round 4
// 79.986 us; speedup vs baseline: 1.0953x; 1.0131x over previous
//
#include <hip/hip_runtime.h>
#include <math.h>

// Geodesic correction, fully analytic (Christoffel contraction collapses since
// v_k v_i is symmetric):  corr = -Hess(g).grad(g),  g(x) = v . mlp(x).
// Per interior point:
//   z = W1^T x + b1 ; t = tanh z ; s = 1-t^2 ; c = W2 v
//   p = c*s ; grad = W1 p ; r = W1^T grad ; q = -2c*t*s ; w = q*r ; corr = -W1 w
//
// Round-12: REVERT to R8 verbatim — the best-measured kernel (79.86 us).
// Evidence trail:
//   R9  (1-kernel + agent-scope handshake): 87.6 us. Agent release/acquire
//       lowers to per-block L2 wb/inv on gfx950 -> kills W1q L2 locality.
//   R11 (LDS-staged W1q + pk_fma + split k_prep): 81.0 us. W1q was already
//       L2-resident and TLP-hidden; staging added a serial vmcnt(0) drain
//       (Common-mistake #7). k_prep split added LDS round-trip for latency
//       that 8 waves/SIMD already hid.
// Conclusion: exec is at its TLP-saturated floor; remaining time is 40.5 us
// harness poison-fill (82% HBM peak) + ~3.3 us/node x 10 graph nodes + ~7 us
// exec floor. Two-kernel structure is optimal under the node-vs-L2 tradeoff.
// Accounting model (fits R2-R11): dur = 40 us fill + 33 us nodes + 7 us exec.

#define D64 64

typedef float floatx2 __attribute__((ext_vector_type(2)));

__device__ __forceinline__ floatx2 fp8_lo(unsigned u) {   // bytes 0,1 -> f32
    return __builtin_amdgcn_cvt_pk_f32_fp8(u, false);
}
__device__ __forceinline__ floatx2 fp8_hi(unsigned u) {   // bytes 2,3 -> f32
    return __builtin_amdgcn_cvt_pk_f32_fp8(u, true);
}
__device__ __forceinline__ unsigned char f2fp8(float x) {
    return (unsigned char)(__builtin_amdgcn_cvt_pk_fp8_f32(x, 0.f, 0, false) & 0xFF);
}

// ---- K0: Z0, Zd, C per b; W1->fp8 and edge rows from b==0 blocks ----
// grid (H/256, B), block 256.
__global__ __launch_bounds__(256) void k_prep(
    const float* __restrict__ x0, const float* __restrict__ xT,
    const float* __restrict__ W1, const float* __restrict__ b1,
    const float* __restrict__ W2,
    unsigned char* __restrict__ W1q,
    float* __restrict__ Z0, float* __restrict__ Zd, float* __restrict__ C,
    float* __restrict__ out, int B, int H, int n_steps)
{
    const int b   = blockIdx.y;
    const int tid = threadIdx.x;
    const int h   = blockIdx.x * 256 + tid;

    __shared__ float x0L[D64], dL[D64], vL[D64];
    if (tid < D64) {
        const float a0 = x0[b * D64 + tid];
        const float aT = xT[b * D64 + tid];
        const float d  = aT - a0;
        float ss = d * d;
        #pragma unroll
        for (int off = 32; off; off >>= 1) ss += __shfl_xor(ss, off);
        const float inv = 1.0f / sqrtf(ss);
        x0L[tid] = a0; dL[tid] = d; vL[tid] = d * inv;
        if (blockIdx.x == 0) {   // edge rows: s=0 -> x0, s=n_steps-1 -> xT
            out[(size_t)(0 * B + b) * D64 + tid]             = a0;
            out[(size_t)((n_steps - 1) * B + b) * D64 + tid] = aT;
        }
    }
    __syncthreads();

    float z0 = b1[h];
    float zd = 0.f;
    if (b == 0) {                 // also emit fp8 W1 (grid-uniform branch)
        #pragma unroll
        for (int d = 0; d < D64; ++d) {
            const float w = W1[(size_t)d * H + h];
            W1q[(size_t)d * H + h] = f2fp8(w);
            z0 = fmaf(x0L[d], w, z0);
            zd = fmaf(dL[d],  w, zd);
        }
    } else {
        #pragma unroll
        for (int d = 0; d < D64; ++d) {
            const float w = W1[(size_t)d * H + h];
            z0 = fmaf(x0L[d], w, z0);
            zd = fmaf(dL[d],  w, zd);
        }
    }

    float c = 0.f;
    const float4* w2r = reinterpret_cast<const float4*>(W2 + (size_t)h * D64);
    #pragma unroll
    for (int i = 0; i < D64 / 4; ++i) {
        const float4 w = w2r[i];
        c = fmaf(w.x, vL[4*i],     c);
        c = fmaf(w.y, vL[4*i + 1], c);
        c = fmaf(w.z, vL[4*i + 2], c);
        c = fmaf(w.w, vL[4*i + 3], c);
    }

    Z0[(size_t)b * H + h] = z0;
    Zd[(size_t)b * H + h] = zd;
    C [(size_t)b * H + h] = c;
}

// ---- K1: fused p/q rebuild + grad/r/w/corr/output, one block per point ----
// grid NP=256, block 1024 (16 waves). W1 consumed as fp8 e4m3 from L2.
// Rowdots: one uint = 4 fp8 k-values pairs with one conflict-free float4 LDS
// read (16 B lane stride) — layouts align naturally at fp8 width.
__global__ __launch_bounds__(1024) void k_fused(
    const float* __restrict__ x0, const float* __restrict__ xT,
    const unsigned char* __restrict__ W1q,
    const float* __restrict__ Z0, const float* __restrict__ Zd,
    const float* __restrict__ C,
    float* __restrict__ out, int B, int H, int n_steps)
{
    const int n    = blockIdx.x;          // (s-1)*B + b
    const int s8   = n / B;
    const int b    = n % B;
    const int tid  = threadIdx.x;
    const int lane = tid & 63;
    const int wv   = tid >> 6;            // 16 waves

    __shared__ float pL[2048];            // p, then reused for w
    __shared__ float qL[2048];
    __shared__ float gradL[D64];
    __shared__ float corrL[D64];

    const float ts = (float)(s8 + 1) / (float)(n_steps - 1);

    // ---- rebuild p, q for this point (2 h's per thread) ----
    {
        const float2 z0 = reinterpret_cast<const float2*>(Z0 + (size_t)b * H)[tid];
        const float2 zd = reinterpret_cast<const float2*>(Zd + (size_t)b * H)[tid];
        const float2 c  = reinterpret_cast<const float2*>(C  + (size_t)b * H)[tid];
        const float zx = fmaf(ts, zd.x, z0.x);
        const float zy = fmaf(ts, zd.y, z0.y);
        const float tx = tanhf(zx), ty = tanhf(zy);
        const float sx = 1.f - tx * tx, sy = 1.f - ty * ty;
        pL[2 * tid]     = c.x * sx;
        pL[2 * tid + 1] = c.y * sy;
        qL[2 * tid]     = -2.f * c.x * tx * sx;
        qL[2 * tid + 1] = -2.f * c.y * ty * sy;
    }
    __syncthreads();

    // ---- grad_a = sum_h W1[a,h] p_h : wave wv -> rows 4wv..4wv+3 ----
    #pragma unroll
    for (int rr = 0; rr < 4; ++rr) {
        const int a = wv * 4 + rr;
        const unsigned* wrow = reinterpret_cast<const unsigned*>(W1q + (size_t)a * H);
        float acc = 0.f;
        #pragma unroll
        for (int j = 0; j < 8; ++j) {     // k = 4*lane + 256*j
            const unsigned w  = wrow[lane + j * 64];       // fp8 k..k+3
            const float4   p  = reinterpret_cast<const float4*>(pL)[lane + j * 64];
            const floatx2  w0 = fp8_lo(w);
            const floatx2  w1 = fp8_hi(w);
            acc = fmaf(w0.x, p.x, acc);
            acc = fmaf(w0.y, p.y, acc);
            acc = fmaf(w1.x, p.z, acc);
            acc = fmaf(w1.y, p.w, acc);
        }
        #pragma unroll
        for (int off = 32; off; off >>= 1) acc += __shfl_xor(acc, off);
        if (lane == 0) gradL[a] = acc;
    }
    __syncthreads();

    // ---- r_h = sum_d W1[d,h] grad_d ; w_h = q_h * r_h (into pL) ----
    {
        float2 r = make_float2(0.f, 0.f);
        #pragma unroll 16
        for (int d = 0; d < D64; ++d) {
            const unsigned w = *reinterpret_cast<const unsigned short*>(
                                   W1q + (size_t)d * H + 2 * tid);
            const floatx2 wf = fp8_lo(w);          // bytes 0,1 = h, h+1
            const float    g = gradL[d];           // LDS broadcast: free
            r.x = fmaf(g, wf.x, r.x);
            r.y = fmaf(g, wf.y, r.y);
        }
        pL[2 * tid]     = qL[2 * tid]     * r.x;
        pL[2 * tid + 1] = qL[2 * tid + 1] * r.y;
    }
    __syncthreads();

    // ---- corr_a = -sum_h W1[a,h] w_h ----
    #pragma unroll
    for (int rr = 0; rr < 4; ++rr) {
        const int a = wv * 4 + rr;
        const unsigned* wrow = reinterpret_cast<const unsigned*>(W1q + (size_t)a * H);
        float acc = 0.f;
        #pragma unroll
        for (int j = 0; j < 8; ++j) {
            const unsigned w  = wrow[lane + j * 64];
            const float4   p  = reinterpret_cast<const float4*>(pL)[lane + j * 64];
            const floatx2  w0 = fp8_lo(w);
            const floatx2  w1 = fp8_hi(w);
            acc = fmaf(w0.x, p.x, acc);
            acc = fmaf(w0.y, p.y, acc);
            acc = fmaf(w1.x, p.z, acc);
            acc = fmaf(w1.y, p.w, acc);
        }
        #pragma unroll
        for (int off = 32; off; off >>= 1) acc += __shfl_xor(acc, off);
        if (lane == 0) corrL[a] = -acc;
    }
    __syncthreads();

    // ---- epilogue (wave 0): scale & write ----
    if (tid < D64) {
        const float a0 = x0[b * D64 + tid];
        const float aT = xT[b * D64 + tid];
        const float d  = aT - a0;
        const float cm = corrL[tid];
        float n2 = cm * cm;
        #pragma unroll
        for (int off = 32; off; off >>= 1) n2 += __shfl_xor(n2, off);
        const float scale  = fminf(sqrtf(n2), 0.1f);
        const float factor = ts * (1.f - ts) * scale * 0.1f;
        out[(size_t)((s8 + 1) * B + b) * D64 + tid] = fmaf(cm, factor, fmaf(ts, d, a0));
    }
}

extern "C" void kernel_launch(void* const* d_in, const int* in_sizes, int n_in,
                              void* d_out, int out_size, void* d_ws, size_t ws_size,
                              hipStream_t stream) {
    const float* x0 = (const float*)d_in[0];
    const float* xT = (const float*)d_in[1];
    const float* W1 = (const float*)d_in[2];
    const float* b1 = (const float*)d_in[3];
    const float* W2 = (const float*)d_in[4];
    float* out = (float*)d_out;

    const int H       = in_sizes[3];            // 2048
    const int D       = in_sizes[2] / H;        // 64
    const int B       = in_sizes[0] / D;        // 32
    const int n_steps = out_size / (B * D);     // 10
    const int NI      = n_steps - 2;            // 8
    const int NP      = NI * B;                 // 256

    // ws layout: W1q[D*H] fp8 | Z0[B*H] f32 | Zd[B*H] f32 | C[B*H] f32
    unsigned char* W1q = (unsigned char*)d_ws;
    float* Z0 = (float*)(W1q + (size_t)D * H);  // 128 KB offset, 4B-aligned
    float* Zd = Z0 + (size_t)B * H;
    float* C  = Zd + (size_t)B * H;

    k_prep<<<dim3(H / 256, B), dim3(256), 0, stream>>>(
        x0, xT, W1, b1, W2, W1q, Z0, Zd, C, out, B, H, n_steps);
    k_fused<<<dim3(NP), dim3(1024), 0, stream>>>(
        x0, xT, W1q, Z0, Zd, C, out, B, H, n_steps);
}